// Round 1
// baseline (1632.024 us; speedup 1.0000x reference)
//
#include <hip/hip_runtime.h>

#define N_NODES 100000
#define N_EDGES 1600000
#define IN_DIM 165
#define HID 64
#define OUT_DIM 2

// ---------------- degree + norm ----------------
__global__ void k_deg(const int* __restrict__ dst, float* __restrict__ deg) {
    int e = blockIdx.x * blockDim.x + threadIdx.x;
    if (e < N_EDGES) atomicAdd(&deg[dst[e]], 1.0f);
}

__global__ void k_dinv(float* __restrict__ deg_dinv) {
    int i = blockIdx.x * blockDim.x + threadIdx.x;
    if (i < N_NODES) deg_dinv[i] = 1.0f / sqrtf(deg_dinv[i] + 1.0f);
}

// ---------------- GEMM1: hw1 = x @ W1  (N x 165) @ (165 x 64) ----------------
__global__ __launch_bounds__(256) void k_gemm1(const float* __restrict__ x,
                                               const float* __restrict__ W1,
                                               float* __restrict__ hw1) {
    __shared__ __align__(16) float xs[64 * IN_DIM];
    __shared__ __align__(16) float ws[IN_DIM * HID];
    const int tid = threadIdx.x;
    const int base = blockIdx.x * 64;
    const int nrows = min(64, N_NODES - base);
    const int cnt = nrows * IN_DIM;
    const float* xg = x + (size_t)base * IN_DIM;
    for (int i = tid; i < cnt; i += 256) xs[i] = xg[i];
    for (int i = tid; i < IN_DIM * HID; i += 256) ws[i] = W1[i];
    __syncthreads();

    const int tr = tid >> 4;   // 0..15 -> rows 4*tr..4*tr+3
    const int tc = tid & 15;   // 0..15 -> cols 4*tc..4*tc+3
    float acc[4][4] = {};
    for (int k = 0; k < IN_DIM; ++k) {
        float4 wv = *(const float4*)&ws[k * HID + 4 * tc];
        #pragma unroll
        for (int i = 0; i < 4; ++i) {
            float xv = xs[(4 * tr + i) * IN_DIM + k];
            acc[i][0] += xv * wv.x;
            acc[i][1] += xv * wv.y;
            acc[i][2] += xv * wv.z;
            acc[i][3] += xv * wv.w;
        }
    }
    #pragma unroll
    for (int i = 0; i < 4; ++i) {
        int r = base + 4 * tr + i;
        if (r < N_NODES) {
            float4 o = {acc[i][0], acc[i][1], acc[i][2], acc[i][3]};
            *(float4*)&hw1[(size_t)r * HID + 4 * tc] = o;
        }
    }
}

// ---------------- layer-1 edge aggregation (COO + atomics) ----------------
// unit u = (edge e, quarter q): 16 units/edge, each handles 4 features
__global__ void k_agg1(const int* __restrict__ src, const int* __restrict__ dst,
                       const float* __restrict__ dinv,
                       const float* __restrict__ hw1, float* __restrict__ agg1) {
    int u = blockIdx.x * blockDim.x + threadIdx.x;  // E*16 = 25.6M < 2^31
    if (u >= N_EDGES * 16) return;
    int e = u >> 4, q = u & 15;
    int s = src[e], d = dst[e];
    float norm = dinv[s] * dinv[d];
    float4 v = *(const float4*)&hw1[(size_t)s * HID + 4 * q];
    float* a = &agg1[(size_t)d * HID + 4 * q];
    atomicAdd(a + 0, v.x * norm);
    atomicAdd(a + 1, v.y * norm);
    atomicAdd(a + 2, v.z * norm);
    atomicAdd(a + 3, v.w * norm);
}

// ---------------- fused epilogue1 + GEMM2:  hw2 = relu(agg1 + hw1*sn + b1) @ W2 ----------------
__global__ __launch_bounds__(256) void k_epi1(const float* __restrict__ agg1,
                                              const float* __restrict__ hw1,
                                              const float* __restrict__ dinv,
                                              const float* __restrict__ b1,
                                              const float* __restrict__ W2,
                                              float* __restrict__ hw2) {
    __shared__ float w2s[HID * OUT_DIM];
    __shared__ float b1s[HID];
    const int tid = threadIdx.x;
    if (tid < HID * OUT_DIM) w2s[tid] = W2[tid];
    if (tid < HID) b1s[tid] = b1[tid];
    __syncthreads();

    const int node = blockIdx.x * 16 + (tid >> 4);
    const int q = tid & 15;
    if (node >= N_NODES) return;
    const float sn = dinv[node] * dinv[node];
    float4 a = *(const float4*)&agg1[(size_t)node * HID + 4 * q];
    float4 hv = *(const float4*)&hw1[(size_t)node * HID + 4 * q];
    float av[4] = {a.x, a.y, a.z, a.w};
    float hvv[4] = {hv.x, hv.y, hv.z, hv.w};
    float s0 = 0.f, s1 = 0.f;
    #pragma unroll
    for (int i = 0; i < 4; ++i) {
        int j = 4 * q + i;
        float h = av[i] + hvv[i] * sn + b1s[j];
        h = fmaxf(h, 0.f);
        s0 += h * w2s[2 * j + 0];
        s1 += h * w2s[2 * j + 1];
    }
    #pragma unroll
    for (int off = 8; off >= 1; off >>= 1) {
        s0 += __shfl_down(s0, off, 16);
        s1 += __shfl_down(s1, off, 16);
    }
    if (q == 0) {
        hw2[(size_t)node * 2 + 0] = s0;
        hw2[(size_t)node * 2 + 1] = s1;
    }
}

// ---------------- layer-2 edge aggregation ----------------
__global__ void k_agg2(const int* __restrict__ src, const int* __restrict__ dst,
                       const float* __restrict__ dinv,
                       const float* __restrict__ hw2, float* __restrict__ out) {
    int e = blockIdx.x * blockDim.x + threadIdx.x;
    if (e >= N_EDGES) return;
    int s = src[e], d = dst[e];
    float norm = dinv[s] * dinv[d];
    float2 v = *(const float2*)&hw2[(size_t)s * 2];
    atomicAdd(&out[(size_t)d * 2 + 0], v.x * norm);
    atomicAdd(&out[(size_t)d * 2 + 1], v.y * norm);
}

// ---------------- final: out += hw2*sn + b2 ----------------
__global__ void k_final(const float* __restrict__ hw2, const float* __restrict__ dinv,
                        const float* __restrict__ b2, float* __restrict__ out) {
    int n = blockIdx.x * blockDim.x + threadIdx.x;
    if (n >= N_NODES) return;
    float sn = dinv[n] * dinv[n];
    out[(size_t)n * 2 + 0] += hw2[(size_t)n * 2 + 0] * sn + b2[0];
    out[(size_t)n * 2 + 1] += hw2[(size_t)n * 2 + 1] * sn + b2[1];
}

extern "C" void kernel_launch(void* const* d_in, const int* in_sizes, int n_in,
                              void* d_out, int out_size, void* d_ws, size_t ws_size,
                              hipStream_t stream) {
    const float* x  = (const float*)d_in[0];
    const int*   ei = (const int*)d_in[1];
    const float* W1 = (const float*)d_in[2];
    const float* b1 = (const float*)d_in[3];
    const float* W2 = (const float*)d_in[4];
    const float* b2 = (const float*)d_in[5];
    float* out = (float*)d_out;

    float* ws   = (float*)d_ws;
    float* dinv = ws;                                   // N
    float* hw1  = ws + N_NODES;                         // N*64
    float* agg1 = hw1 + (size_t)N_NODES * HID;          // N*64
    float* hw2  = agg1 + (size_t)N_NODES * HID;         // N*2
    const int* src = ei;
    const int* dst = ei + N_EDGES;

    hipMemsetAsync(dinv, 0, N_NODES * sizeof(float), stream);
    hipMemsetAsync(agg1, 0, (size_t)N_NODES * HID * sizeof(float), stream);
    hipMemsetAsync(d_out, 0, (size_t)N_NODES * OUT_DIM * sizeof(float), stream);

    k_deg<<<(N_EDGES + 255) / 256, 256, 0, stream>>>(dst, dinv);
    k_dinv<<<(N_NODES + 255) / 256, 256, 0, stream>>>(dinv);
    k_gemm1<<<(N_NODES + 63) / 64, 256, 0, stream>>>(x, W1, hw1);
    k_agg1<<<(N_EDGES * 16 + 255) / 256, 256, 0, stream>>>(src, dst, dinv, hw1, agg1);
    k_epi1<<<(N_NODES + 15) / 16, 256, 0, stream>>>(agg1, hw1, dinv, b1, W2, hw2);
    k_agg2<<<(N_EDGES + 255) / 256, 256, 0, stream>>>(src, dst, dinv, hw2, out);
    k_final<<<(N_NODES + 255) / 256, 256, 0, stream>>>(hw2, dinv, b2, out);
}

// Round 2
// 330.184 us; speedup vs baseline: 4.9428x; 4.9428x over previous
//
#include <hip/hip_runtime.h>

#define N_NODES 100000
#define N_EDGES 1600000
#define IN_DIM 165
#define HID 64
#define OUT_DIM 2
#define SCAN_BLOCKS ((N_NODES + 255) / 256)   // 391

// ---------------- degree histogram (int) ----------------
__global__ void k_hist(const int* __restrict__ dst, int* __restrict__ cnt) {
    int e = blockIdx.x * blockDim.x + threadIdx.x;
    if (e < N_EDGES) atomicAdd(&cnt[dst[e]], 1);
}

__global__ void k_dinv(const int* __restrict__ cnt, float* __restrict__ dinv) {
    int i = blockIdx.x * blockDim.x + threadIdx.x;
    if (i < N_NODES) dinv[i] = rsqrtf((float)cnt[i] + 1.0f);
}

// ---------------- exclusive scan (3 kernels) ----------------
__global__ void k_scan1(const int* __restrict__ cnt, int* __restrict__ excl,
                        int* __restrict__ partials) {
    __shared__ int lds[256];
    const int tid = threadIdx.x;
    const int i = blockIdx.x * 256 + tid;
    int v = (i < N_NODES) ? cnt[i] : 0;
    lds[tid] = v;
    __syncthreads();
    for (int off = 1; off < 256; off <<= 1) {
        int t = (tid >= off) ? lds[tid - off] : 0;
        __syncthreads();
        lds[tid] += t;
        __syncthreads();
    }
    if (i < N_NODES) excl[i] = lds[tid] - v;
    if (tid == 255) partials[blockIdx.x] = lds[255];
}

__global__ void k_scan2(int* __restrict__ partials) {
    __shared__ int lds[512];
    const int tid = threadIdx.x;
    int v = (tid < SCAN_BLOCKS) ? partials[tid] : 0;
    lds[tid] = v;
    __syncthreads();
    for (int off = 1; off < 512; off <<= 1) {
        int t = (tid >= off) ? lds[tid - off] : 0;
        __syncthreads();
        lds[tid] += t;
        __syncthreads();
    }
    if (tid < SCAN_BLOCKS) partials[tid] = lds[tid] - v;   // exclusive
}

__global__ void k_scan3(const int* __restrict__ excl, const int* __restrict__ partials,
                        int* __restrict__ row_ptr) {
    const int i = blockIdx.x * 256 + threadIdx.x;
    if (i < N_NODES) row_ptr[i] = excl[i] + partials[i >> 8];
    if (i == 0) row_ptr[N_NODES] = N_EDGES;
}

// ---------------- scatter edges into CSR (int atomics on cursors) ----------------
__global__ void k_scatter(const int* __restrict__ src, const int* __restrict__ dst,
                          const float* __restrict__ dinv, const int* __restrict__ row_ptr,
                          int* __restrict__ cursor, int* __restrict__ esrc,
                          float* __restrict__ enorm) {
    int e = blockIdx.x * blockDim.x + threadIdx.x;
    if (e >= N_EDGES) return;
    int s = src[e], d = dst[e];
    int pos = row_ptr[d] + atomicAdd(&cursor[d], 1);
    esrc[pos] = s;
    enorm[pos] = dinv[s] * dinv[d];
}

// ---------------- GEMM1: hw1 = x @ W1  (N x 165) @ (165 x 64) ----------------
__global__ __launch_bounds__(256) void k_gemm1(const float* __restrict__ x,
                                               const float* __restrict__ W1,
                                               float* __restrict__ hw1) {
    __shared__ __align__(16) float xs[64 * IN_DIM];
    __shared__ __align__(16) float ws[IN_DIM * HID];
    const int tid = threadIdx.x;
    const int base = blockIdx.x * 64;
    const int nrows = min(64, N_NODES - base);
    const int cnt = nrows * IN_DIM;
    const float* xg = x + (size_t)base * IN_DIM;
    for (int i = tid; i < cnt; i += 256) xs[i] = xg[i];
    for (int i = tid; i < IN_DIM * HID; i += 256) ws[i] = W1[i];
    __syncthreads();

    const int tr = tid >> 4;
    const int tc = tid & 15;
    float acc[4][4] = {};
    for (int k = 0; k < IN_DIM; ++k) {
        float4 wv = *(const float4*)&ws[k * HID + 4 * tc];
        #pragma unroll
        for (int i = 0; i < 4; ++i) {
            float xv = xs[(4 * tr + i) * IN_DIM + k];
            acc[i][0] += xv * wv.x;
            acc[i][1] += xv * wv.y;
            acc[i][2] += xv * wv.z;
            acc[i][3] += xv * wv.w;
        }
    }
    #pragma unroll
    for (int i = 0; i < 4; ++i) {
        int r = base + 4 * tr + i;
        if (r < N_NODES) {
            float4 o = {acc[i][0], acc[i][1], acc[i][2], acc[i][3]};
            *(float4*)&hw1[(size_t)r * HID + 4 * tc] = o;
        }
    }
}

// ---- layer-1 gather aggregation, fused with bias+relu+W2 contraction ----
// 16 lanes/node, 4 features each; per node one pass over its CSR segment.
__global__ __launch_bounds__(256) void k_gather1(const int* __restrict__ row_ptr,
                                                 const int* __restrict__ esrc,
                                                 const float* __restrict__ enorm,
                                                 const float* __restrict__ hw1,
                                                 const float* __restrict__ dinv,
                                                 const float* __restrict__ b1,
                                                 const float* __restrict__ W2,
                                                 float* __restrict__ hw2) {
    __shared__ float w2s[HID * OUT_DIM];
    __shared__ float b1s[HID];
    const int tid = threadIdx.x;
    if (tid < HID * OUT_DIM) w2s[tid] = W2[tid];
    if (tid < HID) b1s[tid] = b1[tid];
    __syncthreads();

    const int node = blockIdx.x * 16 + (tid >> 4);
    const int q = tid & 15;
    if (node >= N_NODES) return;
    const int beg = row_ptr[node], end = row_ptr[node + 1];
    float4 acc = {0.f, 0.f, 0.f, 0.f};
    for (int i = beg; i < end; ++i) {
        int s = esrc[i];
        float w = enorm[i];
        float4 v = *(const float4*)&hw1[(size_t)s * HID + 4 * q];
        acc.x += v.x * w;
        acc.y += v.y * w;
        acc.z += v.z * w;
        acc.w += v.w * w;
    }
    const float sn = dinv[node] * dinv[node];
    float4 hv = *(const float4*)&hw1[(size_t)node * HID + 4 * q];
    float h[4];
    h[0] = fmaxf(acc.x + hv.x * sn + b1s[4 * q + 0], 0.f);
    h[1] = fmaxf(acc.y + hv.y * sn + b1s[4 * q + 1], 0.f);
    h[2] = fmaxf(acc.z + hv.z * sn + b1s[4 * q + 2], 0.f);
    h[3] = fmaxf(acc.w + hv.w * sn + b1s[4 * q + 3], 0.f);
    float s0 = 0.f, s1 = 0.f;
    #pragma unroll
    for (int i = 0; i < 4; ++i) {
        int j = 4 * q + i;
        s0 += h[i] * w2s[2 * j + 0];
        s1 += h[i] * w2s[2 * j + 1];
    }
    #pragma unroll
    for (int off = 8; off >= 1; off >>= 1) {
        s0 += __shfl_down(s0, off, 16);
        s1 += __shfl_down(s1, off, 16);
    }
    if (q == 0) {
        hw2[(size_t)node * 2 + 0] = s0;
        hw2[(size_t)node * 2 + 1] = s1;
    }
}

// ---- layer-2 gather aggregation + final bias (writes d_out fully) ----
__global__ void k_gather2(const int* __restrict__ row_ptr, const int* __restrict__ esrc,
                          const float* __restrict__ enorm, const float* __restrict__ hw2,
                          const float* __restrict__ dinv, const float* __restrict__ b2,
                          float* __restrict__ out) {
    int n = blockIdx.x * blockDim.x + threadIdx.x;
    if (n >= N_NODES) return;
    const int beg = row_ptr[n], end = row_ptr[n + 1];
    float a0 = 0.f, a1 = 0.f;
    for (int i = beg; i < end; ++i) {
        int s = esrc[i];
        float w = enorm[i];
        a0 += hw2[(size_t)s * 2 + 0] * w;
        a1 += hw2[(size_t)s * 2 + 1] * w;
    }
    float sn = dinv[n] * dinv[n];
    out[(size_t)n * 2 + 0] = a0 + hw2[(size_t)n * 2 + 0] * sn + b2[0];
    out[(size_t)n * 2 + 1] = a1 + hw2[(size_t)n * 2 + 1] * sn + b2[1];
}

extern "C" void kernel_launch(void* const* d_in, const int* in_sizes, int n_in,
                              void* d_out, int out_size, void* d_ws, size_t ws_size,
                              hipStream_t stream) {
    const float* x  = (const float*)d_in[0];
    const int*   ei = (const int*)d_in[1];
    const float* W1 = (const float*)d_in[2];
    const float* b1 = (const float*)d_in[3];
    const float* W2 = (const float*)d_in[4];
    const float* b2 = (const float*)d_in[5];
    float* out = (float*)d_out;
    const int* src = ei;
    const int* dst = ei + N_EDGES;

    // workspace layout (float4-aligned arrays first)
    char* w = (char*)d_ws;
    float* hw1     = (float*)w;                 w += (size_t)N_NODES * HID * 4;   // 25.6 MB
    float* enorm   = (float*)w;                 w += (size_t)N_EDGES * 4;         // 6.4 MB
    int*   esrc    = (int*)w;                   w += (size_t)N_EDGES * 4;         // 6.4 MB
    float* dinv    = (float*)w;                 w += (size_t)N_NODES * 4;
    float* hw2     = (float*)w;                 w += (size_t)N_NODES * 2 * 4;
    int*   cnt     = (int*)w;                   w += (size_t)N_NODES * 4;
    int*   excl    = (int*)w;                   w += (size_t)N_NODES * 4;
    int*   row_ptr = (int*)w;                   w += (size_t)(N_NODES + 1) * 4;
    int*   cursor  = (int*)w;                   w += (size_t)N_NODES * 4;
    int*   partials= (int*)w;                   w += 512 * 4;

    hipMemsetAsync(cnt, 0, N_NODES * sizeof(int), stream);
    hipMemsetAsync(cursor, 0, N_NODES * sizeof(int), stream);

    k_hist<<<(N_EDGES + 255) / 256, 256, 0, stream>>>(dst, cnt);
    k_dinv<<<(N_NODES + 255) / 256, 256, 0, stream>>>(cnt, dinv);
    k_scan1<<<SCAN_BLOCKS, 256, 0, stream>>>(cnt, excl, partials);
    k_scan2<<<1, 512, 0, stream>>>(partials);
    k_scan3<<<SCAN_BLOCKS, 256, 0, stream>>>(excl, partials, row_ptr);
    k_gemm1<<<(N_NODES + 63) / 64, 256, 0, stream>>>(x, W1, hw1);
    k_scatter<<<(N_EDGES + 255) / 256, 256, 0, stream>>>(src, dst, dinv, row_ptr, cursor, esrc, enorm);
    k_gather1<<<(N_NODES + 15) / 16, 256, 0, stream>>>(row_ptr, esrc, enorm, hw1, dinv, b1, W2, hw2);
    k_gather2<<<(N_NODES + 255) / 256, 256, 0, stream>>>(row_ptr, esrc, enorm, hw2, dinv, b2, out);
}